// Round 1
// baseline (247.944 us; speedup 1.0000x reference)
//
#include <hip/hip_runtime.h>
#include <hip/hip_bf16.h>

#define IN_DIM 128
#define HEADS 4
#define ODIM 32
#define HD (HEADS * ODIM) // 128
#define NEG_SLOPE 0.2f

// Kernel 1: h = x @ W  (one block of 128 threads per node), fused epilogue
// computing s_src[n,h] = <h[n,h,:], a_src[h,:]>, s_dst likewise.
__global__ void __launch_bounds__(128) k_gemm_attn(
    const float* __restrict__ x, const float* __restrict__ W,
    const float* __restrict__ a_src, const float* __restrict__ a_dst,
    float* __restrict__ h, float* __restrict__ s_src, float* __restrict__ s_dst,
    int N)
{
    int n = blockIdx.x;
    if (n >= N) return;
    int j = threadIdx.x; // output column 0..127
    __shared__ float xs[IN_DIM];
    xs[j] = x[(size_t)n * IN_DIM + j];
    __syncthreads();

    float acc = 0.f;
#pragma unroll 16
    for (int k = 0; k < IN_DIM; ++k) {
        acc = fmaf(xs[k], W[k * HD + j], acc);
    }
    h[(size_t)n * HD + j] = acc;

    int head = j >> 5;       // 0..3
    int d = j & 31;          // 0..31
    float ps = acc * a_src[head * ODIM + d];
    float pd = acc * a_dst[head * ODIM + d];
    // reduce within each 32-lane group (width=32 partitions the 64-wide wave)
#pragma unroll
    for (int off = 16; off >= 1; off >>= 1) {
        ps += __shfl_down(ps, off, 32);
        pd += __shfl_down(pd, off, 32);
    }
    if (d == 0) {
        s_src[n * HEADS + head] = ps;
        s_dst[n * HEADS + head] = pd;
    }
}

// Kernel 2: per (edge, head): w = exp(leaky_relu(s_src[src]+s_dst[dst]));
// denom[dst,h] += w  (atomic).
__global__ void __launch_bounds__(256) k_denom(
    const int* __restrict__ src, const int* __restrict__ dst,
    const float* __restrict__ s_src, const float* __restrict__ s_dst,
    float* __restrict__ denom, int E)
{
    int tid = blockIdx.x * blockDim.x + threadIdx.x;
    int e = tid >> 2;        // edge
    int hh = tid & 3;        // head
    if (e >= E) return;
    int s = src[e], t = dst[e];
    float v = s_src[s * HEADS + hh] + s_dst[t * HEADS + hh];
    v = (v > 0.f) ? v : NEG_SLOPE * v;
    float w = __expf(v);
    atomicAdd(&denom[t * HEADS + hh], w);
}

// Kernel 3: 32 lanes per edge. lane d accumulates
// out[dst,d] += 0.25 * sum_h alpha[e,h] * h[src, h*32+d]
__global__ void __launch_bounds__(256) k_aggregate(
    const int* __restrict__ src, const int* __restrict__ dst,
    const float* __restrict__ h,
    const float* __restrict__ s_src, const float* __restrict__ s_dst,
    const float* __restrict__ denom,
    float* __restrict__ out, int E)
{
    int g = (blockIdx.x * blockDim.x + threadIdx.x) >> 5; // edge id
    int d = threadIdx.x & 31;
    if (g >= E) return;
    int s = src[g], t = dst[g];

    float alpha[HEADS];
#pragma unroll
    for (int hh = 0; hh < HEADS; ++hh) {
        float v = s_src[s * HEADS + hh] + s_dst[t * HEADS + hh];
        v = (v > 0.f) ? v : NEG_SLOPE * v;
        float w = __expf(v);
        alpha[hh] = w / (denom[t * HEADS + hh] + 1e-12f);
    }
    float acc = 0.f;
#pragma unroll
    for (int hh = 0; hh < HEADS; ++hh) {
        acc += alpha[hh] * h[(size_t)s * HD + hh * ODIM + d];
    }
    atomicAdd(&out[(size_t)t * ODIM + d], 0.25f * acc);
}

extern "C" void kernel_launch(void* const* d_in, const int* in_sizes, int n_in,
                              void* d_out, int out_size, void* d_ws, size_t ws_size,
                              hipStream_t stream)
{
    const float* x      = (const float*)d_in[0];
    const int*   eidx   = (const int*)d_in[1];
    const float* W      = (const float*)d_in[2];
    const float* a_src  = (const float*)d_in[3];
    const float* a_dst  = (const float*)d_in[4];
    float* out = (float*)d_out;

    const int N = in_sizes[0] / IN_DIM;
    const int E = in_sizes[1] / 2;
    const int* src = eidx;       // edge_index[0, :]
    const int* dst = eidx + E;   // edge_index[1, :]

    // workspace layout (floats): h[N*128] | s_src[N*4] | s_dst[N*4] | denom[N*4]
    float* h     = (float*)d_ws;
    float* s_src = h + (size_t)N * HD;
    float* s_dst = s_src + (size_t)N * HEADS;
    float* denom = s_dst + (size_t)N * HEADS;

    // zero the atomically-accumulated buffers every call (harness poisons once)
    hipMemsetAsync(denom, 0, (size_t)N * HEADS * sizeof(float), stream);
    hipMemsetAsync(out, 0, (size_t)out_size * sizeof(float), stream);

    // 1) h = x@W + attention scalars
    k_gemm_attn<<<N, 128, 0, stream>>>(x, W, a_src, a_dst, h, s_src, s_dst, N);

    // 2) softmax denominators
    {
        int threads = 256;
        int total = E * HEADS;
        int blocks = (total + threads - 1) / threads;
        k_denom<<<blocks, threads, 0, stream>>>(src, dst, s_src, s_dst, denom, E);
    }

    // 3) aggregation (32 lanes per edge)
    {
        int threads = 256;
        long long total = (long long)E * 32;
        int blocks = (int)((total + threads - 1) / threads);
        k_aggregate<<<blocks, threads, 0, stream>>>(src, dst, h, s_src, s_dst, denom, out, E);
    }
}